// Round 4
// baseline (1125.273 us; speedup 1.0000x reference)
//
#include <hip/hip_runtime.h>
#include <hip/hip_bf16.h>

// MDGCL fused pipeline v4 for MI355X.
// v3 -> v4: SpMM gathers vectorized to float4 (16 lanes/row-slice, 4 edges in
// flight per wave instruction, fully predicated groups -> no tail path),
// quarter-parallel epilogue stores. Everything else carried from audited v3:
//  - CSR entries pack (j | 4 dropout flags, adj) -> one sequential 8B read/edge.
//  - layer0: 3 channels from ONE gather; epilogue Ecur_k = E0 + act(a_k),
//    Etot = 2E0 + act(a0).
//  - layer1 full pass channel-0 only: Etot += 2*Ecur0 - E0 + act(a1)
//    (=> Eu_tot = 3E0 + 3z0 + act1, matching the reference recurrence).
//  - layer1 channels 1/2 only needed at 2048 sampled rows -> sampled spmm.
//  - 12 dispatches total.
#define N_Uc 100000
#define N_Ic 50000
#define Dc   64
#define Ec   2000000
#define Bc   2048
#define Kc   10
#define PDROPc   0.2f
#define INV_Tc   5.0f
#define LHYPERc  0.1f
#define JS 4
#define JCH (Bc/JS)

#define NU64 (N_Uc*Dc)
#define NI64 (N_Ic*Dc)
#define B64  (Bc*Dc)

// flag bits: bit17 = keep L0 chA, bit18 = keep L0 chB, bit19 = keep L1 chA,
// bit20 = keep L1 chB. j < 2^17.
#define FB_A0 (1<<17)
#define FB_B0 (1<<18)
#define FB_A1 (1<<19)
#define FB_B1 (1<<20)
#define JMASK 0x1FFFF

// block-range constants (4 rows/block everywhere)
#define NB_SPU (N_Uc/4)          // 25000
#define NB_SPI (N_Ic/4)          // 12500
#define NB_B   (Bc/4)            // 512
#define NTILE_U 49               // ceil(100000/2048)
#define NTILE_I 25               // ceil(50000/2048)
#define NBF_U 391                // cdiv(100000,256)
#define NBF_I 196                // cdiv(50000,256)

static inline int cdiv(int a, int b){ return (a+b-1)/b; }

__device__ __forceinline__ float wsum(float v){
  #pragma unroll
  for (int m=32; m; m>>=1) v += __shfl_xor(v, m, 64);
  return v;
}
__device__ __forceinline__ float actf(float x){ return x >= 0.f ? x : 0.5f*x; }

// ---------------- CSR build ----------------
__global__ __launch_bounds__(256) void k_zero(int* cnt_u, int* cnt_i, float* lacc){
  int i = blockIdx.x*256 + threadIdx.x;
  if (i < N_Uc) cnt_u[i] = 0;
  if (i < N_Ic) cnt_i[i] = 0;
  if (i < 16)   lacc[i]  = 0.f;
}

__global__ __launch_bounds__(256) void k_hist(const int* __restrict__ rows, const int* __restrict__ cols,
                                              int* cnt_u, int* cnt_i){
  int e = blockIdx.x*256 + threadIdx.x;
  if (e < Ec){
    atomicAdd(&cnt_u[rows[e]], 1);
    atomicAdd(&cnt_i[cols[e]], 1);
  }
}

// merged u+i local scan: blocks [0,NTILE_U) -> u, [NTILE_U, NTILE_U+NTILE_I) -> i
__global__ __launch_bounds__(256) void k_scan_local(const int* __restrict__ cnt_u, const int* __restrict__ cnt_i,
                                                    int* __restrict__ ex_u, int* __restrict__ ex_i,
                                                    int* __restrict__ tsum_u, int* __restrict__ tsum_i){
  __shared__ int sh[256];
  const int t = threadIdx.x;
  const bool isU = blockIdx.x < NTILE_U;
  const int tile = isU ? blockIdx.x : blockIdx.x - NTILE_U;
  const int n = isU ? N_Uc : N_Ic;
  const int* cnt = isU ? cnt_u : cnt_i;
  int* excl = isU ? ex_u : ex_i;
  int* tsum = isU ? tsum_u : tsum_i;
  const int base = tile*2048 + t*8;
  int v[8]; int s = 0;
  #pragma unroll
  for (int q=0;q<8;q++){ int idx = base+q; int x = (idx<n)? cnt[idx] : 0; v[q] = s; s += x; }
  sh[t] = s; __syncthreads();
  for (int off=1; off<256; off<<=1){
    int y = (t>=off)? sh[t-off] : 0;
    __syncthreads();
    sh[t] += y;
    __syncthreads();
  }
  const int texcl = (t==0)? 0 : sh[t-1];
  #pragma unroll
  for (int q=0;q<8;q++){ int idx = base+q; if (idx<n) excl[idx] = texcl + v[q]; }
  if (t==255) tsum[tile] = sh[255];
}

// block 0 -> u tiles, block 1 -> i tiles
__global__ __launch_bounds__(256) void k_scan_tiles(int* tsum_u, int* tsum_i){
  __shared__ int sh[256];
  const int t = threadIdx.x;
  int* tsum = blockIdx.x ? tsum_i : tsum_u;
  const int ntiles = blockIdx.x ? NTILE_I : NTILE_U;
  sh[t] = (t<ntiles)? tsum[t] : 0; __syncthreads();
  for (int off=1; off<256; off<<=1){
    int y = (t>=off)? sh[t-off] : 0;
    __syncthreads();
    sh[t] += y;
    __syncthreads();
  }
  if (t<ntiles) tsum[t] = (t==0)? 0 : sh[t-1];
}

__global__ __launch_bounds__(256) void k_scan_final(const int* __restrict__ tsum_u, const int* __restrict__ tsum_i,
                                                    int* __restrict__ ptr_u, int* __restrict__ ptr_i,
                                                    int* __restrict__ cur_u, int* __restrict__ cur_i){
  const bool isU = blockIdx.x < NBF_U;
  const int blk = isU ? blockIdx.x : blockIdx.x - NBF_U;
  const int n = isU ? N_Uc : N_Ic;
  const int* tsum = isU ? tsum_u : tsum_i;
  int* ptr = isU ? ptr_u : ptr_i;
  int* cur = isU ? cur_u : cur_i;
  const int i = blk*256 + threadIdx.x;
  if (i < n){
    int v = cur[i] + tsum[i/2048];
    ptr[i] = v; cur[i] = v;
  }
  if (i == 0) ptr[n] = Ec;
}

__global__ __launch_bounds__(256) void k_scatter(const int* __restrict__ rows, const int* __restrict__ cols,
                                                 const float* __restrict__ adj, const float* __restrict__ keep,
                                                 int* cur_u, int* cur_i,
                                                 int2* __restrict__ ent_u, int2* __restrict__ ent_i){
  int e = blockIdx.x*256 + threadIdx.x;
  if (e < Ec){
    const int r = rows[e], c = cols[e];
    const int ab = __float_as_int(adj[e]);
    const int fu = ((keep[(size_t)0*Ec+e] >= PDROPc)? FB_A0:0) | ((keep[(size_t)2*Ec+e] >= PDROPc)? FB_B0:0)
                 | ((keep[(size_t)4*Ec+e] >= PDROPc)? FB_A1:0) | ((keep[(size_t)6*Ec+e] >= PDROPc)? FB_B1:0);
    const int fi = ((keep[(size_t)1*Ec+e] >= PDROPc)? FB_A0:0) | ((keep[(size_t)3*Ec+e] >= PDROPc)? FB_B0:0)
                 | ((keep[(size_t)5*Ec+e] >= PDROPc)? FB_A1:0) | ((keep[(size_t)7*Ec+e] >= PDROPc)? FB_B1:0);
    const int p = atomicAdd(&cur_u[r], 1); ent_u[p] = make_int2(c | fu, ab);
    const int q = atomicAdd(&cur_i[c], 1); ent_i[q] = make_int2(r | fi, ab);
  }
}

// ---------------- SpMM device helpers (float4 / 16-lane row-slices) ----------------
// Wave layout: qid = lane>>4 (edge-group slot 0..3), m16 = lane&15 (dims 4*m16..+3).
// Per group-iteration a wave covers 4 edges; every sub-step fully predicated.

// layer-0 3-channel body. a0: dropA, a1: adj (S channel), a2: dropB.
__device__ __forceinline__ void dev_spmm3(const int* __restrict__ ptr, const int2* __restrict__ ent,
                                          const float* __restrict__ X, const float* __restrict__ E0,
                                          float* __restrict__ Ec0, float* __restrict__ Ec1,
                                          float* __restrict__ Ec2, float* __restrict__ Etot,
                                          int row, int lane){
  const int beg = ptr[row], end = ptr[row+1];
  const int qid = lane >> 4, m16 = lane & 15;
  float4 a0 = make_float4(0,0,0,0), a1 = a0, a2 = a0;
  for (int base = beg; base < end; base += 64){
    const int rem = end - base;
    int pj = 0; float av = 0.f;
    if (lane < rem){
      const int2 en = ent[base + lane];
      pj = en.x; av = __int_as_float(en.y);
    }
    const int cnt = rem < 64 ? rem : 64;
    for (int g = 0; g < cnt; g += 8){
      // two predicated 4-edge sub-groups -> 2 outstanding dwordx4 loads
      const int iA = g + qid,     iB = g + 4 + qid;          // always < 64
      const int pA = __shfl(pj, iA, 64), pB = __shfl(pj, iB, 64);
      float wA = __shfl(av, iA, 64),     wB = __shfl(av, iB, 64);
      wA = (iA < cnt) ? wA : 0.f;
      wB = (iB < cnt) ? wB : 0.f;
      const float4 xA = *(const float4*)(X + (((size_t)(pA & JMASK)) << 6) + (m16 << 2));
      const float4 xB = *(const float4*)(X + (((size_t)(pB & JMASK)) << 6) + (m16 << 2));
      const float kA = wA*1.25f, kB = wB*1.25f;
      const float aA = (pA & FB_A0)? kA:0.f, bA = (pA & FB_B0)? kA:0.f;
      const float aB = (pB & FB_A0)? kB:0.f, bB = (pB & FB_B0)? kB:0.f;
      a1.x = fmaf(wA,xA.x,a1.x); a1.y = fmaf(wA,xA.y,a1.y); a1.z = fmaf(wA,xA.z,a1.z); a1.w = fmaf(wA,xA.w,a1.w);
      a0.x = fmaf(aA,xA.x,a0.x); a0.y = fmaf(aA,xA.y,a0.y); a0.z = fmaf(aA,xA.z,a0.z); a0.w = fmaf(aA,xA.w,a0.w);
      a2.x = fmaf(bA,xA.x,a2.x); a2.y = fmaf(bA,xA.y,a2.y); a2.z = fmaf(bA,xA.z,a2.z); a2.w = fmaf(bA,xA.w,a2.w);
      a1.x = fmaf(wB,xB.x,a1.x); a1.y = fmaf(wB,xB.y,a1.y); a1.z = fmaf(wB,xB.z,a1.z); a1.w = fmaf(wB,xB.w,a1.w);
      a0.x = fmaf(aB,xB.x,a0.x); a0.y = fmaf(aB,xB.y,a0.y); a0.z = fmaf(aB,xB.z,a0.z); a0.w = fmaf(aB,xB.w,a0.w);
      a2.x = fmaf(bB,xB.x,a2.x); a2.y = fmaf(bB,xB.y,a2.y); a2.z = fmaf(bB,xB.z,a2.z); a2.w = fmaf(bB,xB.w,a2.w);
    }
  }
  // combine the 4 edge-group partials (lanes differing only in qid)
  #pragma unroll
  for (int off = 16; off <= 32; off <<= 1){
    a0.x += __shfl_xor(a0.x, off, 64); a0.y += __shfl_xor(a0.y, off, 64);
    a0.z += __shfl_xor(a0.z, off, 64); a0.w += __shfl_xor(a0.w, off, 64);
    a1.x += __shfl_xor(a1.x, off, 64); a1.y += __shfl_xor(a1.y, off, 64);
    a1.z += __shfl_xor(a1.z, off, 64); a1.w += __shfl_xor(a1.w, off, 64);
    a2.x += __shfl_xor(a2.x, off, 64); a2.y += __shfl_xor(a2.y, off, 64);
    a2.z += __shfl_xor(a2.z, off, 64); a2.w += __shfl_xor(a2.w, off, 64);
  }
  const size_t o = ((size_t)row << 6) + (m16 << 2);
  const float4 e0 = *(const float4*)(E0 + o);
  // quarter-parallel epilogue: quarter q writes channel q
  if (qid == 0){
    float4 r; r.x = e0.x+actf(a0.x); r.y = e0.y+actf(a0.y); r.z = e0.z+actf(a0.z); r.w = e0.w+actf(a0.w);
    *(float4*)(Ec0 + o) = r;
  } else if (qid == 1){
    float4 r; r.x = e0.x+actf(a1.x); r.y = e0.y+actf(a1.y); r.z = e0.z+actf(a1.z); r.w = e0.w+actf(a1.w);
    *(float4*)(Ec1 + o) = r;
  } else if (qid == 2){
    float4 r; r.x = e0.x+actf(a2.x); r.y = e0.y+actf(a2.y); r.z = e0.z+actf(a2.z); r.w = e0.w+actf(a2.w);
    *(float4*)(Ec2 + o) = r;
  } else {
    float4 r; r.x = 2.f*e0.x+actf(a0.x); r.y = 2.f*e0.y+actf(a0.y); r.z = 2.f*e0.z+actf(a0.z); r.w = 2.f*e0.w+actf(a0.w);
    *(float4*)(Etot + o) = r;
  }
}

// layer-1 channel-0 body. Etot += 2*D0 - E0 + act(a0).
__device__ __forceinline__ void dev_spmm1(const int* __restrict__ ptr, const int2* __restrict__ ent,
                                          const float* __restrict__ S, const float* __restrict__ D0,
                                          const float* __restrict__ E0, float* __restrict__ Etot,
                                          int row, int lane){
  const int beg = ptr[row], end = ptr[row+1];
  const int qid = lane >> 4, m16 = lane & 15;
  float4 a0 = make_float4(0,0,0,0);
  for (int base = beg; base < end; base += 64){
    const int rem = end - base;
    int pj = 0; float av = 0.f;
    if (lane < rem){
      const int2 en = ent[base + lane];
      pj = en.x; av = __int_as_float(en.y);
    }
    const int cnt = rem < 64 ? rem : 64;
    for (int g = 0; g < cnt; g += 8){
      const int iA = g + qid,     iB = g + 4 + qid;
      const int pA = __shfl(pj, iA, 64), pB = __shfl(pj, iB, 64);
      float wA = __shfl(av, iA, 64),     wB = __shfl(av, iB, 64);
      wA = (iA < cnt && (pA & FB_A1)) ? wA*1.25f : 0.f;
      wB = (iB < cnt && (pB & FB_A1)) ? wB*1.25f : 0.f;
      const float4 xA = *(const float4*)(S + (((size_t)(pA & JMASK)) << 6) + (m16 << 2));
      const float4 xB = *(const float4*)(S + (((size_t)(pB & JMASK)) << 6) + (m16 << 2));
      a0.x = fmaf(wA,xA.x,a0.x); a0.y = fmaf(wA,xA.y,a0.y); a0.z = fmaf(wA,xA.z,a0.z); a0.w = fmaf(wA,xA.w,a0.w);
      a0.x = fmaf(wB,xB.x,a0.x); a0.y = fmaf(wB,xB.y,a0.y); a0.z = fmaf(wB,xB.z,a0.z); a0.w = fmaf(wB,xB.w,a0.w);
    }
  }
  #pragma unroll
  for (int off = 16; off <= 32; off <<= 1){
    a0.x += __shfl_xor(a0.x, off, 64); a0.y += __shfl_xor(a0.y, off, 64);
    a0.z += __shfl_xor(a0.z, off, 64); a0.w += __shfl_xor(a0.w, off, 64);
  }
  if (qid == 0){
    const size_t o = ((size_t)row << 6) + (m16 << 2);
    const float4 d0 = *(const float4*)(D0 + o);
    const float4 e0 = *(const float4*)(E0 + o);
    float4 et = *(float4*)(Etot + o);
    et.x += 2.f*d0.x - e0.x + actf(a0.x);
    et.y += 2.f*d0.y - e0.y + actf(a0.y);
    et.z += 2.f*d0.z - e0.z + actf(a0.z);
    et.w += 2.f*d0.w - e0.w + actf(a0.w);
    *(float4*)(Etot + o) = et;
  }
}

// sampled 3-channel layer-1 body (2048 rows/side), scalar (tiny traffic).
__device__ __forceinline__ void dev_sspmm(const int* __restrict__ ids, const int* __restrict__ ptr,
                                          const int2* __restrict__ ent,
                                          const float* __restrict__ S0, const float* __restrict__ S1,
                                          const float* __restrict__ S2,
                                          const float* __restrict__ D0, const float* __restrict__ D1,
                                          const float* __restrict__ D2, const float* __restrict__ E0,
                                          float* __restrict__ o0, float* __restrict__ o1,
                                          float* __restrict__ o2, int idx, int lane){
  const int row = ids[idx];
  const int beg = ptr[row], end = ptr[row+1];
  float a0=0.f, a1=0.f, a2=0.f;
  for (int base = beg; base < end; base += 64){
    const int rem = end - base;
    int pj = 0; float av = 0.f;
    if (lane < rem){
      const int2 en = ent[base + lane];
      pj = en.x; av = __int_as_float(en.y);
    }
    const int cnt = rem < 64 ? rem : 64;
    for (int tt=0; tt<cnt; ++tt){
      const int   p = __shfl(pj,tt,64);
      const float w = __shfl(av,tt,64);
      const size_t co = ((size_t)(p&JMASK)<<6)+lane;
      const float x0 = S0[co], x1 = S1[co], x2 = S2[co];
      a1 = fmaf(w, x1, a1);
      a0 = fmaf((p&FB_A1)? w*1.25f:0.f, x0, a0);
      a2 = fmaf((p&FB_B1)? w*1.25f:0.f, x2, a2);
    }
  }
  const size_t o  = ((size_t)idx << 6) + lane;
  const size_t ro = ((size_t)row << 6) + lane;
  const float e0 = E0[ro];
  o0[o] = actf(a0) + D0[ro] - e0;
  o1[o] = actf(a1) + D1[ro] - e0;
  o2[o] = actf(a2) + D2[ro] - e0;
}

__device__ __forceinline__ void dev_gsave0(const int* __restrict__ ids,
                                           const float* __restrict__ D0, const float* __restrict__ D1,
                                           const float* __restrict__ D2, const float* __restrict__ E0,
                                           float* __restrict__ o0, float* __restrict__ o1,
                                           float* __restrict__ o2, int idx, int lane){
  const size_t ro = ((size_t)ids[idx] << 6) + lane;
  const size_t o  = ((size_t)idx << 6) + lane;
  const float e0 = E0[ro];
  o0[o] = D0[ro] - e0; o1[o] = D1[ro] - e0; o2[o] = D2[ro] - e0;
}

// ---------------- merged top-level kernels ----------------
struct SpmmArgs {
  const int* ptr_u; const int2* ent_u;
  const int* ptr_i; const int2* ent_i;
  const float* Eu0; const float* Ei0;
  float* Ecu0; float* Ecu1; float* Ecu2; float* Eut;
  float* Eci0; float* Eci1; float* Eci2; float* Eit;
};

// layer 0: blocks [0,25000) u-dst, [25000,37500) i-dst
__global__ __launch_bounds__(256) void k_spmm3_all(SpmmArgs a){
  const int w = threadIdx.x >> 6, lane = threadIdx.x & 63;
  const int bid = blockIdx.x;
  if (bid < NB_SPU){
    const int row = bid*4 + w;
    dev_spmm3(a.ptr_u, a.ent_u, a.Ei0, a.Eu0, a.Ecu0, a.Ecu1, a.Ecu2, a.Eut, row, lane);
  } else {
    const int row = (bid-NB_SPU)*4 + w;
    dev_spmm3(a.ptr_i, a.ent_i, a.Eu0, a.Ei0, a.Eci0, a.Eci1, a.Eci2, a.Eit, row, lane);
  }
}

struct L1Args {
  const int* ptr_u; const int2* ent_u;
  const int* ptr_i; const int2* ent_i;
  const float* Eu0; const float* Ei0;
  const float* Ecu0; const float* Ecu1; const float* Ecu2;
  const float* Eci0; const float* Eci1; const float* Eci2;
  float* Eut; float* Eit;
  const int* uids; const int* iids;
  float* svu1_0; float* svu1_1; float* svu1_2;   // layer-1 saves u (zu1, zsu1, zuu1)
  float* svi1_0; float* svi1_1; float* svi1_2;
  float* svu0_0; float* svu0_1; float* svu0_2;   // layer-0 saves u
  float* svi0_0; float* svi0_1; float* svi0_2;
};

// layer 1 + sampled + layer-0 gathers, one grid:
// [0,25000) spmm1 u | [25000,37500) spmm1 i | [37500,38012) sspmm u |
// [38012,38524) sspmm i | [38524,39036) gsave0 u | [39036,39548) gsave0 i
__global__ __launch_bounds__(256) void k_layer1_all(L1Args a){
  const int w = threadIdx.x >> 6, lane = threadIdx.x & 63;
  const int bid = blockIdx.x;
  if (bid < NB_SPU){
    dev_spmm1(a.ptr_u, a.ent_u, a.Eci0, a.Ecu0, a.Eu0, a.Eut, bid*4+w, lane);
  } else if (bid < NB_SPU+NB_SPI){
    dev_spmm1(a.ptr_i, a.ent_i, a.Ecu0, a.Eci0, a.Ei0, a.Eit, (bid-NB_SPU)*4+w, lane);
  } else if (bid < NB_SPU+NB_SPI+NB_B){
    dev_sspmm(a.uids, a.ptr_u, a.ent_u, a.Eci0, a.Eci1, a.Eci2,
              a.Ecu0, a.Ecu1, a.Ecu2, a.Eu0, a.svu1_0, a.svu1_1, a.svu1_2,
              (bid-(NB_SPU+NB_SPI))*4+w, lane);
  } else if (bid < NB_SPU+NB_SPI+2*NB_B){
    dev_sspmm(a.iids, a.ptr_i, a.ent_i, a.Ecu0, a.Ecu1, a.Ecu2,
              a.Eci0, a.Eci1, a.Eci2, a.Ei0, a.svi1_0, a.svi1_1, a.svi1_2,
              (bid-(NB_SPU+NB_SPI+NB_B))*4+w, lane);
  } else if (bid < NB_SPU+NB_SPI+3*NB_B){
    dev_gsave0(a.uids, a.Ecu0, a.Ecu1, a.Ecu2, a.Eu0,
               a.svu0_0, a.svu0_1, a.svu0_2, (bid-(NB_SPU+NB_SPI+2*NB_B))*4+w, lane);
  } else {
    dev_gsave0(a.iids, a.Eci0, a.Eci1, a.Eci2, a.Ei0,
               a.svi0_0, a.svi0_1, a.svi0_2, (bid-(NB_SPU+NB_SPI+3*NB_B))*4+w, lane);
  }
}

// ---------------- loss prep: 12 ops x 512 blocks ----------------
// ops 0..3: normalize z (-> G) | 4..7: normalize zuu/zii (-> H graph) |
// 8..11: hprep (-> H hyper). op p = l*2+side.
struct PrepArgs {
  const float* in[12];
  const float* W[12];
  float* out[12];
};

__global__ __launch_bounds__(256) void k_prep(PrepArgs pa){
  const int op = blockIdx.x >> 9;
  const int sub = blockIdx.x & 511;
  const int w = threadIdx.x >> 6, lane = threadIdx.x & 63;
  const int b = sub*4 + w;
  const float* in = pa.in[op];
  float* out = pa.out[op];
  const size_t o = ((size_t)b << 6) + lane;
  if (op < 8){
    const float v = in[o];
    const float n = fmaxf(sqrtf(wsum(v*v)), 1e-12f);
    out[o] = v/n;
  } else {
    const float* W = pa.W[op];
    const float x  = in[o];
    const float xn = fmaxf(sqrtf(wsum(x*x)), 1e-7f);
    const float sh = sinhf(xn), ch = coshf(xn);
    float vp = sh * x / xn;
    const float nv = fmaxf(sqrtf(ch*ch + wsum(vp*vp)), 1e-12f);
    const float v0 = ch/nv;
    vp /= nv;
    float acc = v0 * W[lane + 1];
    #pragma unroll
    for (int r=0; r<64; ++r){
      const float vr = __shfl(vp, r, 64);
      acc = fmaf(vr, W[(r+1)*65 + lane + 1], acc);
    }
    out[o] = acc;
  }
}

// ---------------- pair scores (8 pairs, 2-row register blocking) + lossr ----------------
// blocks [0,4096): pairIdx = bid>>9; wid = bid&511; rgroup = wid>>2 (16 rows), jb = wid&3.
// blocks [4096,4608): loss_r.
struct PairArgs {
  const float* G[8]; const float* H[8];
  float2* pp;                       // [8][Bc][JS]
  const int* uids; const int* pos; const int* neg;
  const float* Eut; const float* Eit;
  float* lacc;
};

__global__ __launch_bounds__(256,2) void k_pair_all(PairArgs pa){
  __shared__ float h_sh[64][68];
  const int bid = blockIdx.x;
  const int t = threadIdx.x;
  if (bid >= 4096){
    const int b = (bid-4096)*4 + (t>>6);
    const int lane = t & 63;
    const float ue = pa.Eut[((size_t)pa.uids[b] << 6) + lane];
    float s = 0.f;
    #pragma unroll
    for (int k=0;k<Kc;k++){
      const float dp = wsum(ue * pa.Eit[((size_t)pa.pos[b*Kc+k] << 6) + lane]);
      const float dn = wsum(ue * pa.Eit[((size_t)pa.neg[b*Kc+k] << 6) + lane]);
      const float tt = 1.f - dp + dn;
      s += tt > 0.f ? tt : 0.f;
    }
    if (lane == 0) atomicAdd(&pa.lacc[0], s);
    return;
  }
  const int pIdx = bid >> 9;
  const int wid = bid & 511;
  const int rg = wid >> 2, jb = wid & 3;
  const float* G = pa.G[pIdx];
  const float* H = pa.H[pIdx];
  const int rp = t >> 5, c = t & 31;
  const int r0 = rg*16 + rp*2;
  float4 g0[16], g1[16];
  {
    const float4* G0 = (const float4*)(G + ((size_t)r0 << 6));
    const float4* G1 = (const float4*)(G + ((size_t)(r0+1) << 6));
    #pragma unroll
    for (int q=0;q<16;q++){ g0[q] = G0[q]; g1[q] = G1[q]; }
  }
  float m0=-1e30f, s0=0.f, m1=-1e30f, s1=0.f;
  for (int jt = jb*JCH; jt < jb*JCH + JCH; jt += 64){
    __syncthreads();
    #pragma unroll
    for (int q0=0;q0<4;q0++){
      const int q = t + q0*256;
      const int row = q >> 4, col = q & 15;
      *(float4*)&h_sh[row][col*4] = ((const float4*)(H + ((size_t)(jt+row) << 6)))[col];
    }
    __syncthreads();
    #pragma unroll
    for (int jj=0; jj<2; ++jj){
      const int j = jj*32 + c;
      float d0 = 0.f, d1 = 0.f;
      #pragma unroll
      for (int q=0;q<16;q++){
        const float4 hv = *(const float4*)&h_sh[j][q*4];
        d0 = fmaf(g0[q].x, hv.x, d0); d0 = fmaf(g0[q].y, hv.y, d0);
        d0 = fmaf(g0[q].z, hv.z, d0); d0 = fmaf(g0[q].w, hv.w, d0);
        d1 = fmaf(g1[q].x, hv.x, d1); d1 = fmaf(g1[q].y, hv.y, d1);
        d1 = fmaf(g1[q].z, hv.z, d1); d1 = fmaf(g1[q].w, hv.w, d1);
      }
      d0 *= INV_Tc; d1 *= INV_Tc;
      { const float M = fmaxf(m0, d0); s0 = fmaf(s0, __expf(m0-M), __expf(d0-M)); m0 = M; }
      { const float M = fmaxf(m1, d1); s1 = fmaf(s1, __expf(m1-M), __expf(d1-M)); m1 = M; }
    }
  }
  #pragma unroll
  for (int off=16; off; off>>=1){
    { const float mo=__shfl_xor(m0,off,64), so=__shfl_xor(s0,off,64);
      const float M=fmaxf(m0,mo); s0 = s0*__expf(m0-M) + so*__expf(mo-M); m0=M; }
    { const float mo=__shfl_xor(m1,off,64), so=__shfl_xor(s1,off,64);
      const float M=fmaxf(m1,mo); s1 = s1*__expf(m1-M) + so*__expf(mo-M); m1=M; }
  }
  if (c == 0){
    float2* pp = pa.pp + (size_t)pIdx*Bc*JS;
    pp[(size_t)r0*JS + jb]     = make_float2(m0, s0);
    pp[(size_t)(r0+1)*JS + jb] = make_float2(m1, s1);
  }
}

// merge: 8 x 512 blocks; kind = pIdx&1 (0: loss_g->slot2, 1: loss_h->slot1)
struct MergeArgs {
  const float* G[8]; const float* H[8];
  const float2* pp; float* lacc;
};

__global__ __launch_bounds__(256) void k_merge_all(MergeArgs ma){
  const int pIdx = blockIdx.x >> 9;
  const int sub = blockIdx.x & 511;
  const int w = threadIdx.x >> 6, lane = threadIdx.x & 63;
  const int b = sub*4 + w;
  const float* G = ma.G[pIdx];
  const float* H = ma.H[pIdx];
  const size_t o = ((size_t)b << 6) + lane;
  const float d = wsum(G[o]*H[o]) * INV_Tc;
  const float2* pp = ma.pp + (size_t)pIdx*Bc*JS + (size_t)b*JS;
  const float2 p0 = pp[0], p1 = pp[1], p2 = pp[2], p3 = pp[3];
  float res; int slot;
  if ((pIdx & 1) == 0){
    const float M = fmaxf(fmaxf(p0.x,p1.x), fmaxf(p2.x,p3.x));
    const float S = p0.y*__expf(p0.x-M) + p1.y*__expf(p1.x-M)
                  + p2.y*__expf(p2.x-M) + p3.y*__expf(p3.x-M);
    res = M + logf(S) - d;
    slot = 2;
  } else {
    const float S = p0.y*__expf(p0.x) + p1.y*__expf(p1.x)
                  + p2.y*__expf(p2.x) + p3.y*__expf(p3.x);
    res = -logf(__expf(d)/(S + 1e-8f) + 1e-8f);
    slot = 1;
  }
  if (lane == 0) atomicAdd(&ma.lacc[slot], res);
}

__global__ void k_final(const float* __restrict__ lacc, float* __restrict__ out){
  if (threadIdx.x == 0 && blockIdx.x == 0){
    const float lr = lacc[0] / (float)Bc;
    const float lh = lacc[1];
    const float lg = lacc[2];
    out[0] = lr + LHYPERc*lh + lg;
    out[1] = lr; out[2] = lh; out[3] = lg;
  }
}

// ---------------- host launch ----------------
extern "C" void kernel_launch(void* const* d_in, const int* in_sizes, int n_in,
                              void* d_out, int out_size, void* d_ws, size_t ws_size,
                              hipStream_t stream){
  const float* E_u0 = (const float*)d_in[0];
  const float* E_i0 = (const float*)d_in[1];
  // d_in[2], d_in[3] (S_u_0, S_i_0): col 0 == 0 forever, payload == E_*_0 -> unused.
  const float* Ws   = (const float*)d_in[4];
  const float* adj  = (const float*)d_in[5];
  const float* keep = (const float*)d_in[6];
  const int* rows = (const int*)d_in[7];
  const int* cols = (const int*)d_in[8];
  const int* uids = (const int*)d_in[9];
  const int* iids = (const int*)d_in[10];
  const int* pos  = (const int*)d_in[11];
  const int* neg  = (const int*)d_in[12];
  float* out = (float*)d_out;

  char* wsb = (char*)d_ws;
  size_t off = 0;
  auto alloc = [&](size_t bytes)->void*{
    void* p = (void*)(wsb + off);
    off += (bytes + 255) & ~(size_t)255;
    return p;
  };

  int* cnt_u = (int*)alloc((size_t)N_Uc*4);
  int* ptr_u = (int*)alloc((size_t)(N_Uc+1)*4);
  int* cur_u = (int*)alloc((size_t)N_Uc*4);
  int* cnt_i = (int*)alloc((size_t)N_Ic*4);
  int* ptr_i = (int*)alloc((size_t)(N_Ic+1)*4);
  int* cur_i = (int*)alloc((size_t)N_Ic*4);
  int2* ent_u = (int2*)alloc((size_t)Ec*8);
  int2* ent_i = (int2*)alloc((size_t)Ec*8);
  int* tsum_u = (int*)alloc(256*4);
  int* tsum_i = (int*)alloc(256*4);

  float* Ecu0 = (float*)alloc((size_t)NU64*4);
  float* Ecu1 = (float*)alloc((size_t)NU64*4);
  float* Ecu2 = (float*)alloc((size_t)NU64*4);
  float* Eu_t = (float*)alloc((size_t)NU64*4);
  float* Eci0 = (float*)alloc((size_t)NI64*4);
  float* Eci1 = (float*)alloc((size_t)NI64*4);
  float* Eci2 = (float*)alloc((size_t)NI64*4);
  float* Ei_t = (float*)alloc((size_t)NI64*4);

  // saves: [layer][channel] per side (channels: 0=z, 1=zs, 2=zuu/zii)
  float* sv_u[2][3], *sv_i[2][3];
  for (int l=0;l<2;l++) for (int ch=0;ch<3;ch++){
    sv_u[l][ch] = (float*)alloc((size_t)B64*4);
    sv_i[l][ch] = (float*)alloc((size_t)B64*4);
  }
  // prep outputs: per (l,side) p: nrm_g[p], nrm_u[p], hmat[p]
  float* nrm_g[4], *nrm_u[4], *hmat[4];
  for (int p=0;p<4;p++){
    nrm_g[p] = (float*)alloc((size_t)B64*4);
    nrm_u[p] = (float*)alloc((size_t)B64*4);
    hmat[p]  = (float*)alloc((size_t)B64*4);
  }
  float2* pp = (float2*)alloc((size_t)8*Bc*JS*8);
  float* lacc = (float*)alloc(64*4);
  // total ws use ~= 203 MB

  // ---- CSR/CSC build (6 launches) ----
  k_zero<<<NBF_U,256,0,stream>>>(cnt_u, cnt_i, lacc);
  k_hist<<<cdiv(Ec,256),256,0,stream>>>(rows, cols, cnt_u, cnt_i);
  k_scan_local<<<NTILE_U+NTILE_I,256,0,stream>>>(cnt_u, cnt_i, cur_u, cur_i, tsum_u, tsum_i);
  k_scan_tiles<<<2,256,0,stream>>>(tsum_u, tsum_i);
  k_scan_final<<<NBF_U+NBF_I,256,0,stream>>>(tsum_u, tsum_i, ptr_u, ptr_i, cur_u, cur_i);
  k_scatter<<<cdiv(Ec,256),256,0,stream>>>(rows, cols, adj, keep, cur_u, cur_i, ent_u, ent_i);

  // ---- layer 0 (1 launch) ----
  SpmmArgs sa{ptr_u, ent_u, ptr_i, ent_i, E_u0, E_i0,
              Ecu0, Ecu1, Ecu2, Eu_t, Eci0, Eci1, Eci2, Ei_t};
  k_spmm3_all<<<NB_SPU+NB_SPI,256,0,stream>>>(sa);

  // ---- layer 1 + sampled + layer-0 saves (1 launch) ----
  L1Args la{ptr_u, ent_u, ptr_i, ent_i, E_u0, E_i0,
            Ecu0, Ecu1, Ecu2, Eci0, Eci1, Eci2, Eu_t, Ei_t, uids, iids,
            sv_u[1][0], sv_u[1][1], sv_u[1][2], sv_i[1][0], sv_i[1][1], sv_i[1][2],
            sv_u[0][0], sv_u[0][1], sv_u[0][2], sv_i[0][0], sv_i[0][1], sv_i[0][2]};
  k_layer1_all<<<NB_SPU+NB_SPI+4*NB_B,256,0,stream>>>(la);

  // ---- loss prep (1 launch): p = l*2+side ----
  PrepArgs pra{};
  for (int l=0;l<2;l++) for (int side=0; side<2; side++){
    const int p = l*2+side;
    float** svs = side ? sv_i[l] : sv_u[l];
    pra.in[p]   = svs[0]; pra.out[p]   = nrm_g[p];
    pra.in[4+p] = svs[2]; pra.out[4+p] = nrm_u[p];
    pra.in[8+p] = svs[1]; pra.out[8+p] = hmat[p];
    pra.W[8+p]  = Ws + (size_t)l*65*65;
  }
  k_prep<<<12*NB_B,256,0,stream>>>(pra);

  // ---- pair scores + lossr (1 launch) ----
  PairArgs paa{};
  for (int p=0;p<4;p++){
    paa.G[2*p]   = nrm_g[p]; paa.H[2*p]   = nrm_u[p];   // loss_g
    paa.G[2*p+1] = nrm_g[p]; paa.H[2*p+1] = hmat[p];    // loss_h
  }
  paa.pp = pp; paa.uids = uids; paa.pos = pos; paa.neg = neg;
  paa.Eut = Eu_t; paa.Eit = Ei_t; paa.lacc = lacc;
  k_pair_all<<<4096+NB_B,256,0,stream>>>(paa);

  // ---- merge (1 launch) + final ----
  MergeArgs mga{};
  for (int p=0;p<8;p++){ mga.G[p] = paa.G[p]; mga.H[p] = paa.H[p]; }
  mga.pp = pp; mga.lacc = lacc;
  k_merge_all<<<8*NB_B,256,0,stream>>>(mga);

  k_final<<<1,64,0,stream>>>(lacc, out);
}

// Round 5
// 935.661 us; speedup vs baseline: 1.2026x; 1.2026x over previous
//
#include <hip/hip_runtime.h>
#include <hip/hip_bf16.h>

// MDGCL fused pipeline v5 for MI355X.
// v4 -> v5: removed ALL contended atomics (k_merge_all was 210us = 19% of
// total, serialized on 16K same-address atomicAdds at 1.2% VALUBusy).
// loss partials now go to unique slots (rbuf / mres), summed by a single
// 1-block tree-reduction kernel. Everything else identical to v4 (which
// passed with absmax=0.0).
#define N_Uc 100000
#define N_Ic 50000
#define Dc   64
#define Ec   2000000
#define Bc   2048
#define Kc   10
#define PDROPc   0.2f
#define INV_Tc   5.0f
#define LHYPERc  0.1f
#define JS 4
#define JCH (Bc/JS)

#define NU64 (N_Uc*Dc)
#define NI64 (N_Ic*Dc)
#define B64  (Bc*Dc)

// flag bits: bit17 = keep L0 chA, bit18 = keep L0 chB, bit19 = keep L1 chA,
// bit20 = keep L1 chB. j < 2^17.
#define FB_A0 (1<<17)
#define FB_B0 (1<<18)
#define FB_A1 (1<<19)
#define FB_B1 (1<<20)
#define JMASK 0x1FFFF

// block-range constants (4 rows/block everywhere)
#define NB_SPU (N_Uc/4)          // 25000
#define NB_SPI (N_Ic/4)          // 12500
#define NB_B   (Bc/4)            // 512
#define NTILE_U 49               // ceil(100000/2048)
#define NTILE_I 25               // ceil(50000/2048)
#define NBF_U 391                // cdiv(100000,256)
#define NBF_I 196                // cdiv(50000,256)

static inline int cdiv(int a, int b){ return (a+b-1)/b; }

__device__ __forceinline__ float wsum(float v){
  #pragma unroll
  for (int m=32; m; m>>=1) v += __shfl_xor(v, m, 64);
  return v;
}
__device__ __forceinline__ float actf(float x){ return x >= 0.f ? x : 0.5f*x; }

// ---------------- CSR build ----------------
__global__ __launch_bounds__(256) void k_zero(int* cnt_u, int* cnt_i){
  int i = blockIdx.x*256 + threadIdx.x;
  if (i < N_Uc) cnt_u[i] = 0;
  if (i < N_Ic) cnt_i[i] = 0;
}

__global__ __launch_bounds__(256) void k_hist(const int* __restrict__ rows, const int* __restrict__ cols,
                                              int* cnt_u, int* cnt_i){
  int e = blockIdx.x*256 + threadIdx.x;
  if (e < Ec){
    atomicAdd(&cnt_u[rows[e]], 1);
    atomicAdd(&cnt_i[cols[e]], 1);
  }
}

// merged u+i local scan: blocks [0,NTILE_U) -> u, [NTILE_U, NTILE_U+NTILE_I) -> i
__global__ __launch_bounds__(256) void k_scan_local(const int* __restrict__ cnt_u, const int* __restrict__ cnt_i,
                                                    int* __restrict__ ex_u, int* __restrict__ ex_i,
                                                    int* __restrict__ tsum_u, int* __restrict__ tsum_i){
  __shared__ int sh[256];
  const int t = threadIdx.x;
  const bool isU = blockIdx.x < NTILE_U;
  const int tile = isU ? blockIdx.x : blockIdx.x - NTILE_U;
  const int n = isU ? N_Uc : N_Ic;
  const int* cnt = isU ? cnt_u : cnt_i;
  int* excl = isU ? ex_u : ex_i;
  int* tsum = isU ? tsum_u : tsum_i;
  const int base = tile*2048 + t*8;
  int v[8]; int s = 0;
  #pragma unroll
  for (int q=0;q<8;q++){ int idx = base+q; int x = (idx<n)? cnt[idx] : 0; v[q] = s; s += x; }
  sh[t] = s; __syncthreads();
  for (int off=1; off<256; off<<=1){
    int y = (t>=off)? sh[t-off] : 0;
    __syncthreads();
    sh[t] += y;
    __syncthreads();
  }
  const int texcl = (t==0)? 0 : sh[t-1];
  #pragma unroll
  for (int q=0;q<8;q++){ int idx = base+q; if (idx<n) excl[idx] = texcl + v[q]; }
  if (t==255) tsum[tile] = sh[255];
}

// block 0 -> u tiles, block 1 -> i tiles
__global__ __launch_bounds__(256) void k_scan_tiles(int* tsum_u, int* tsum_i){
  __shared__ int sh[256];
  const int t = threadIdx.x;
  int* tsum = blockIdx.x ? tsum_i : tsum_u;
  const int ntiles = blockIdx.x ? NTILE_I : NTILE_U;
  sh[t] = (t<ntiles)? tsum[t] : 0; __syncthreads();
  for (int off=1; off<256; off<<=1){
    int y = (t>=off)? sh[t-off] : 0;
    __syncthreads();
    sh[t] += y;
    __syncthreads();
  }
  if (t<ntiles) tsum[t] = (t==0)? 0 : sh[t-1];
}

__global__ __launch_bounds__(256) void k_scan_final(const int* __restrict__ tsum_u, const int* __restrict__ tsum_i,
                                                    int* __restrict__ ptr_u, int* __restrict__ ptr_i,
                                                    int* __restrict__ cur_u, int* __restrict__ cur_i){
  const bool isU = blockIdx.x < NBF_U;
  const int blk = isU ? blockIdx.x : blockIdx.x - NBF_U;
  const int n = isU ? N_Uc : N_Ic;
  const int* tsum = isU ? tsum_u : tsum_i;
  int* ptr = isU ? ptr_u : ptr_i;
  int* cur = isU ? cur_u : cur_i;
  const int i = blk*256 + threadIdx.x;
  if (i < n){
    int v = cur[i] + tsum[i/2048];
    ptr[i] = v; cur[i] = v;
  }
  if (i == 0) ptr[n] = Ec;
}

__global__ __launch_bounds__(256) void k_scatter(const int* __restrict__ rows, const int* __restrict__ cols,
                                                 const float* __restrict__ adj, const float* __restrict__ keep,
                                                 int* cur_u, int* cur_i,
                                                 int2* __restrict__ ent_u, int2* __restrict__ ent_i){
  int e = blockIdx.x*256 + threadIdx.x;
  if (e < Ec){
    const int r = rows[e], c = cols[e];
    const int ab = __float_as_int(adj[e]);
    const int fu = ((keep[(size_t)0*Ec+e] >= PDROPc)? FB_A0:0) | ((keep[(size_t)2*Ec+e] >= PDROPc)? FB_B0:0)
                 | ((keep[(size_t)4*Ec+e] >= PDROPc)? FB_A1:0) | ((keep[(size_t)6*Ec+e] >= PDROPc)? FB_B1:0);
    const int fi = ((keep[(size_t)1*Ec+e] >= PDROPc)? FB_A0:0) | ((keep[(size_t)3*Ec+e] >= PDROPc)? FB_B0:0)
                 | ((keep[(size_t)5*Ec+e] >= PDROPc)? FB_A1:0) | ((keep[(size_t)7*Ec+e] >= PDROPc)? FB_B1:0);
    const int p = atomicAdd(&cur_u[r], 1); ent_u[p] = make_int2(c | fu, ab);
    const int q = atomicAdd(&cur_i[c], 1); ent_i[q] = make_int2(r | fi, ab);
  }
}

// ---------------- SpMM device helpers (float4 / 16-lane row-slices) ----------------
// Wave layout: qid = lane>>4 (edge-group slot 0..3), m16 = lane&15 (dims 4*m16..+3).

// layer-0 3-channel body. a0: dropA, a1: adj (S channel), a2: dropB.
__device__ __forceinline__ void dev_spmm3(const int* __restrict__ ptr, const int2* __restrict__ ent,
                                          const float* __restrict__ X, const float* __restrict__ E0,
                                          float* __restrict__ Ec0, float* __restrict__ Ec1,
                                          float* __restrict__ Ec2, float* __restrict__ Etot,
                                          int row, int lane){
  const int beg = ptr[row], end = ptr[row+1];
  const int qid = lane >> 4, m16 = lane & 15;
  float4 a0 = make_float4(0,0,0,0), a1 = a0, a2 = a0;
  for (int base = beg; base < end; base += 64){
    const int rem = end - base;
    int pj = 0; float av = 0.f;
    if (lane < rem){
      const int2 en = ent[base + lane];
      pj = en.x; av = __int_as_float(en.y);
    }
    const int cnt = rem < 64 ? rem : 64;
    for (int g = 0; g < cnt; g += 8){
      const int iA = g + qid,     iB = g + 4 + qid;          // always < 64
      const int pA = __shfl(pj, iA, 64), pB = __shfl(pj, iB, 64);
      float wA = __shfl(av, iA, 64),     wB = __shfl(av, iB, 64);
      wA = (iA < cnt) ? wA : 0.f;
      wB = (iB < cnt) ? wB : 0.f;
      const float4 xA = *(const float4*)(X + (((size_t)(pA & JMASK)) << 6) + (m16 << 2));
      const float4 xB = *(const float4*)(X + (((size_t)(pB & JMASK)) << 6) + (m16 << 2));
      const float kA = wA*1.25f, kB = wB*1.25f;
      const float aA = (pA & FB_A0)? kA:0.f, bA = (pA & FB_B0)? kA:0.f;
      const float aB = (pB & FB_A0)? kB:0.f, bB = (pB & FB_B0)? kB:0.f;
      a1.x = fmaf(wA,xA.x,a1.x); a1.y = fmaf(wA,xA.y,a1.y); a1.z = fmaf(wA,xA.z,a1.z); a1.w = fmaf(wA,xA.w,a1.w);
      a0.x = fmaf(aA,xA.x,a0.x); a0.y = fmaf(aA,xA.y,a0.y); a0.z = fmaf(aA,xA.z,a0.z); a0.w = fmaf(aA,xA.w,a0.w);
      a2.x = fmaf(bA,xA.x,a2.x); a2.y = fmaf(bA,xA.y,a2.y); a2.z = fmaf(bA,xA.z,a2.z); a2.w = fmaf(bA,xA.w,a2.w);
      a1.x = fmaf(wB,xB.x,a1.x); a1.y = fmaf(wB,xB.y,a1.y); a1.z = fmaf(wB,xB.z,a1.z); a1.w = fmaf(wB,xB.w,a1.w);
      a0.x = fmaf(aB,xB.x,a0.x); a0.y = fmaf(aB,xB.y,a0.y); a0.z = fmaf(aB,xB.z,a0.z); a0.w = fmaf(aB,xB.w,a0.w);
      a2.x = fmaf(bB,xB.x,a2.x); a2.y = fmaf(bB,xB.y,a2.y); a2.z = fmaf(bB,xB.z,a2.z); a2.w = fmaf(bB,xB.w,a2.w);
    }
  }
  #pragma unroll
  for (int off = 16; off <= 32; off <<= 1){
    a0.x += __shfl_xor(a0.x, off, 64); a0.y += __shfl_xor(a0.y, off, 64);
    a0.z += __shfl_xor(a0.z, off, 64); a0.w += __shfl_xor(a0.w, off, 64);
    a1.x += __shfl_xor(a1.x, off, 64); a1.y += __shfl_xor(a1.y, off, 64);
    a1.z += __shfl_xor(a1.z, off, 64); a1.w += __shfl_xor(a1.w, off, 64);
    a2.x += __shfl_xor(a2.x, off, 64); a2.y += __shfl_xor(a2.y, off, 64);
    a2.z += __shfl_xor(a2.z, off, 64); a2.w += __shfl_xor(a2.w, off, 64);
  }
  const size_t o = ((size_t)row << 6) + (m16 << 2);
  const float4 e0 = *(const float4*)(E0 + o);
  if (qid == 0){
    float4 r; r.x = e0.x+actf(a0.x); r.y = e0.y+actf(a0.y); r.z = e0.z+actf(a0.z); r.w = e0.w+actf(a0.w);
    *(float4*)(Ec0 + o) = r;
  } else if (qid == 1){
    float4 r; r.x = e0.x+actf(a1.x); r.y = e0.y+actf(a1.y); r.z = e0.z+actf(a1.z); r.w = e0.w+actf(a1.w);
    *(float4*)(Ec1 + o) = r;
  } else if (qid == 2){
    float4 r; r.x = e0.x+actf(a2.x); r.y = e0.y+actf(a2.y); r.z = e0.z+actf(a2.z); r.w = e0.w+actf(a2.w);
    *(float4*)(Ec2 + o) = r;
  } else {
    float4 r; r.x = 2.f*e0.x+actf(a0.x); r.y = 2.f*e0.y+actf(a0.y); r.z = 2.f*e0.z+actf(a0.z); r.w = 2.f*e0.w+actf(a0.w);
    *(float4*)(Etot + o) = r;
  }
}

// layer-1 channel-0 body. Etot += 2*D0 - E0 + act(a0).
__device__ __forceinline__ void dev_spmm1(const int* __restrict__ ptr, const int2* __restrict__ ent,
                                          const float* __restrict__ S, const float* __restrict__ D0,
                                          const float* __restrict__ E0, float* __restrict__ Etot,
                                          int row, int lane){
  const int beg = ptr[row], end = ptr[row+1];
  const int qid = lane >> 4, m16 = lane & 15;
  float4 a0 = make_float4(0,0,0,0);
  for (int base = beg; base < end; base += 64){
    const int rem = end - base;
    int pj = 0; float av = 0.f;
    if (lane < rem){
      const int2 en = ent[base + lane];
      pj = en.x; av = __int_as_float(en.y);
    }
    const int cnt = rem < 64 ? rem : 64;
    for (int g = 0; g < cnt; g += 8){
      const int iA = g + qid,     iB = g + 4 + qid;
      const int pA = __shfl(pj, iA, 64), pB = __shfl(pj, iB, 64);
      float wA = __shfl(av, iA, 64),     wB = __shfl(av, iB, 64);
      wA = (iA < cnt && (pA & FB_A1)) ? wA*1.25f : 0.f;
      wB = (iB < cnt && (pB & FB_A1)) ? wB*1.25f : 0.f;
      const float4 xA = *(const float4*)(S + (((size_t)(pA & JMASK)) << 6) + (m16 << 2));
      const float4 xB = *(const float4*)(S + (((size_t)(pB & JMASK)) << 6) + (m16 << 2));
      a0.x = fmaf(wA,xA.x,a0.x); a0.y = fmaf(wA,xA.y,a0.y); a0.z = fmaf(wA,xA.z,a0.z); a0.w = fmaf(wA,xA.w,a0.w);
      a0.x = fmaf(wB,xB.x,a0.x); a0.y = fmaf(wB,xB.y,a0.y); a0.z = fmaf(wB,xB.z,a0.z); a0.w = fmaf(wB,xB.w,a0.w);
    }
  }
  #pragma unroll
  for (int off = 16; off <= 32; off <<= 1){
    a0.x += __shfl_xor(a0.x, off, 64); a0.y += __shfl_xor(a0.y, off, 64);
    a0.z += __shfl_xor(a0.z, off, 64); a0.w += __shfl_xor(a0.w, off, 64);
  }
  if (qid == 0){
    const size_t o = ((size_t)row << 6) + (m16 << 2);
    const float4 d0 = *(const float4*)(D0 + o);
    const float4 e0 = *(const float4*)(E0 + o);
    float4 et = *(float4*)(Etot + o);
    et.x += 2.f*d0.x - e0.x + actf(a0.x);
    et.y += 2.f*d0.y - e0.y + actf(a0.y);
    et.z += 2.f*d0.z - e0.z + actf(a0.z);
    et.w += 2.f*d0.w - e0.w + actf(a0.w);
    *(float4*)(Etot + o) = et;
  }
}

// sampled 3-channel layer-1 body (2048 rows/side), scalar (tiny traffic).
__device__ __forceinline__ void dev_sspmm(const int* __restrict__ ids, const int* __restrict__ ptr,
                                          const int2* __restrict__ ent,
                                          const float* __restrict__ S0, const float* __restrict__ S1,
                                          const float* __restrict__ S2,
                                          const float* __restrict__ D0, const float* __restrict__ D1,
                                          const float* __restrict__ D2, const float* __restrict__ E0,
                                          float* __restrict__ o0, float* __restrict__ o1,
                                          float* __restrict__ o2, int idx, int lane){
  const int row = ids[idx];
  const int beg = ptr[row], end = ptr[row+1];
  float a0=0.f, a1=0.f, a2=0.f;
  for (int base = beg; base < end; base += 64){
    const int rem = end - base;
    int pj = 0; float av = 0.f;
    if (lane < rem){
      const int2 en = ent[base + lane];
      pj = en.x; av = __int_as_float(en.y);
    }
    const int cnt = rem < 64 ? rem : 64;
    for (int tt=0; tt<cnt; ++tt){
      const int   p = __shfl(pj,tt,64);
      const float w = __shfl(av,tt,64);
      const size_t co = ((size_t)(p&JMASK)<<6)+lane;
      const float x0 = S0[co], x1 = S1[co], x2 = S2[co];
      a1 = fmaf(w, x1, a1);
      a0 = fmaf((p&FB_A1)? w*1.25f:0.f, x0, a0);
      a2 = fmaf((p&FB_B1)? w*1.25f:0.f, x2, a2);
    }
  }
  const size_t o  = ((size_t)idx << 6) + lane;
  const size_t ro = ((size_t)row << 6) + lane;
  const float e0 = E0[ro];
  o0[o] = actf(a0) + D0[ro] - e0;
  o1[o] = actf(a1) + D1[ro] - e0;
  o2[o] = actf(a2) + D2[ro] - e0;
}

__device__ __forceinline__ void dev_gsave0(const int* __restrict__ ids,
                                           const float* __restrict__ D0, const float* __restrict__ D1,
                                           const float* __restrict__ D2, const float* __restrict__ E0,
                                           float* __restrict__ o0, float* __restrict__ o1,
                                           float* __restrict__ o2, int idx, int lane){
  const size_t ro = ((size_t)ids[idx] << 6) + lane;
  const size_t o  = ((size_t)idx << 6) + lane;
  const float e0 = E0[ro];
  o0[o] = D0[ro] - e0; o1[o] = D1[ro] - e0; o2[o] = D2[ro] - e0;
}

// ---------------- merged top-level kernels ----------------
struct SpmmArgs {
  const int* ptr_u; const int2* ent_u;
  const int* ptr_i; const int2* ent_i;
  const float* Eu0; const float* Ei0;
  float* Ecu0; float* Ecu1; float* Ecu2; float* Eut;
  float* Eci0; float* Eci1; float* Eci2; float* Eit;
};

// layer 0: blocks [0,25000) u-dst, [25000,37500) i-dst
__global__ __launch_bounds__(256) void k_spmm3_all(SpmmArgs a){
  const int w = threadIdx.x >> 6, lane = threadIdx.x & 63;
  const int bid = blockIdx.x;
  if (bid < NB_SPU){
    const int row = bid*4 + w;
    dev_spmm3(a.ptr_u, a.ent_u, a.Ei0, a.Eu0, a.Ecu0, a.Ecu1, a.Ecu2, a.Eut, row, lane);
  } else {
    const int row = (bid-NB_SPU)*4 + w;
    dev_spmm3(a.ptr_i, a.ent_i, a.Eu0, a.Ei0, a.Eci0, a.Eci1, a.Eci2, a.Eit, row, lane);
  }
}

struct L1Args {
  const int* ptr_u; const int2* ent_u;
  const int* ptr_i; const int2* ent_i;
  const float* Eu0; const float* Ei0;
  const float* Ecu0; const float* Ecu1; const float* Ecu2;
  const float* Eci0; const float* Eci1; const float* Eci2;
  float* Eut; float* Eit;
  const int* uids; const int* iids;
  float* svu1_0; float* svu1_1; float* svu1_2;   // layer-1 saves u (zu1, zsu1, zuu1)
  float* svi1_0; float* svi1_1; float* svi1_2;
  float* svu0_0; float* svu0_1; float* svu0_2;   // layer-0 saves u
  float* svi0_0; float* svi0_1; float* svi0_2;
};

// layer 1 + sampled + layer-0 gathers, one grid:
// [0,25000) spmm1 u | [25000,37500) spmm1 i | [37500,38012) sspmm u |
// [38012,38524) sspmm i | [38524,39036) gsave0 u | [39036,39548) gsave0 i
__global__ __launch_bounds__(256) void k_layer1_all(L1Args a){
  const int w = threadIdx.x >> 6, lane = threadIdx.x & 63;
  const int bid = blockIdx.x;
  if (bid < NB_SPU){
    dev_spmm1(a.ptr_u, a.ent_u, a.Eci0, a.Ecu0, a.Eu0, a.Eut, bid*4+w, lane);
  } else if (bid < NB_SPU+NB_SPI){
    dev_spmm1(a.ptr_i, a.ent_i, a.Ecu0, a.Eci0, a.Ei0, a.Eit, (bid-NB_SPU)*4+w, lane);
  } else if (bid < NB_SPU+NB_SPI+NB_B){
    dev_sspmm(a.uids, a.ptr_u, a.ent_u, a.Eci0, a.Eci1, a.Eci2,
              a.Ecu0, a.Ecu1, a.Ecu2, a.Eu0, a.svu1_0, a.svu1_1, a.svu1_2,
              (bid-(NB_SPU+NB_SPI))*4+w, lane);
  } else if (bid < NB_SPU+NB_SPI+2*NB_B){
    dev_sspmm(a.iids, a.ptr_i, a.ent_i, a.Ecu0, a.Ecu1, a.Ecu2,
              a.Eci0, a.Eci1, a.Eci2, a.Ei0, a.svi1_0, a.svi1_1, a.svi1_2,
              (bid-(NB_SPU+NB_SPI+NB_B))*4+w, lane);
  } else if (bid < NB_SPU+NB_SPI+3*NB_B){
    dev_gsave0(a.uids, a.Ecu0, a.Ecu1, a.Ecu2, a.Eu0,
               a.svu0_0, a.svu0_1, a.svu0_2, (bid-(NB_SPU+NB_SPI+2*NB_B))*4+w, lane);
  } else {
    dev_gsave0(a.iids, a.Eci0, a.Eci1, a.Eci2, a.Ei0,
               a.svi0_0, a.svi0_1, a.svi0_2, (bid-(NB_SPU+NB_SPI+3*NB_B))*4+w, lane);
  }
}

// ---------------- loss prep: 12 ops x 512 blocks ----------------
struct PrepArgs {
  const float* in[12];
  const float* W[12];
  float* out[12];
};

__global__ __launch_bounds__(256) void k_prep(PrepArgs pa){
  const int op = blockIdx.x >> 9;
  const int sub = blockIdx.x & 511;
  const int w = threadIdx.x >> 6, lane = threadIdx.x & 63;
  const int b = sub*4 + w;
  const float* in = pa.in[op];
  float* out = pa.out[op];
  const size_t o = ((size_t)b << 6) + lane;
  if (op < 8){
    const float v = in[o];
    const float n = fmaxf(sqrtf(wsum(v*v)), 1e-12f);
    out[o] = v/n;
  } else {
    const float* W = pa.W[op];
    const float x  = in[o];
    const float xn = fmaxf(sqrtf(wsum(x*x)), 1e-7f);
    const float sh = sinhf(xn), ch = coshf(xn);
    float vp = sh * x / xn;
    const float nv = fmaxf(sqrtf(ch*ch + wsum(vp*vp)), 1e-12f);
    const float v0 = ch/nv;
    vp /= nv;
    float acc = v0 * W[lane + 1];
    #pragma unroll
    for (int r=0; r<64; ++r){
      const float vr = __shfl(vp, r, 64);
      acc = fmaf(vr, W[(r+1)*65 + lane + 1], acc);
    }
    out[o] = acc;
  }
}

// ---------------- pair scores (8 pairs, 2-row register blocking) + lossr ----------------
// blocks [0,4096): pairIdx = bid>>9; wid = bid&511; rgroup = wid>>2 (16 rows), jb = wid&3.
// blocks [4096,4608): loss_r -> rbuf[b] (unique slot, no atomics).
struct PairArgs {
  const float* G[8]; const float* H[8];
  float2* pp;                       // [8][Bc][JS]
  const int* uids; const int* pos; const int* neg;
  const float* Eut; const float* Eit;
  float* rbuf;                      // [Bc] loss_r partials
};

__global__ __launch_bounds__(256,2) void k_pair_all(PairArgs pa){
  __shared__ float h_sh[64][68];
  const int bid = blockIdx.x;
  const int t = threadIdx.x;
  if (bid >= 4096){
    const int b = (bid-4096)*4 + (t>>6);
    const int lane = t & 63;
    const float ue = pa.Eut[((size_t)pa.uids[b] << 6) + lane];
    float s = 0.f;
    #pragma unroll
    for (int k=0;k<Kc;k++){
      const float dp = wsum(ue * pa.Eit[((size_t)pa.pos[b*Kc+k] << 6) + lane]);
      const float dn = wsum(ue * pa.Eit[((size_t)pa.neg[b*Kc+k] << 6) + lane]);
      const float tt = 1.f - dp + dn;
      s += tt > 0.f ? tt : 0.f;
    }
    if (lane == 0) pa.rbuf[b] = s;
    return;
  }
  const int pIdx = bid >> 9;
  const int wid = bid & 511;
  const int rg = wid >> 2, jb = wid & 3;
  const float* G = pa.G[pIdx];
  const float* H = pa.H[pIdx];
  const int rp = t >> 5, c = t & 31;
  const int r0 = rg*16 + rp*2;
  float4 g0[16], g1[16];
  {
    const float4* G0 = (const float4*)(G + ((size_t)r0 << 6));
    const float4* G1 = (const float4*)(G + ((size_t)(r0+1) << 6));
    #pragma unroll
    for (int q=0;q<16;q++){ g0[q] = G0[q]; g1[q] = G1[q]; }
  }
  float m0=-1e30f, s0=0.f, m1=-1e30f, s1=0.f;
  for (int jt = jb*JCH; jt < jb*JCH + JCH; jt += 64){
    __syncthreads();
    #pragma unroll
    for (int q0=0;q0<4;q0++){
      const int q = t + q0*256;
      const int row = q >> 4, col = q & 15;
      *(float4*)&h_sh[row][col*4] = ((const float4*)(H + ((size_t)(jt+row) << 6)))[col];
    }
    __syncthreads();
    #pragma unroll
    for (int jj=0; jj<2; ++jj){
      const int j = jj*32 + c;
      float d0 = 0.f, d1 = 0.f;
      #pragma unroll
      for (int q=0;q<16;q++){
        const float4 hv = *(const float4*)&h_sh[j][q*4];
        d0 = fmaf(g0[q].x, hv.x, d0); d0 = fmaf(g0[q].y, hv.y, d0);
        d0 = fmaf(g0[q].z, hv.z, d0); d0 = fmaf(g0[q].w, hv.w, d0);
        d1 = fmaf(g1[q].x, hv.x, d1); d1 = fmaf(g1[q].y, hv.y, d1);
        d1 = fmaf(g1[q].z, hv.z, d1); d1 = fmaf(g1[q].w, hv.w, d1);
      }
      d0 *= INV_Tc; d1 *= INV_Tc;
      { const float M = fmaxf(m0, d0); s0 = fmaf(s0, __expf(m0-M), __expf(d0-M)); m0 = M; }
      { const float M = fmaxf(m1, d1); s1 = fmaf(s1, __expf(m1-M), __expf(d1-M)); m1 = M; }
    }
  }
  #pragma unroll
  for (int off=16; off; off>>=1){
    { const float mo=__shfl_xor(m0,off,64), so=__shfl_xor(s0,off,64);
      const float M=fmaxf(m0,mo); s0 = s0*__expf(m0-M) + so*__expf(mo-M); m0=M; }
    { const float mo=__shfl_xor(m1,off,64), so=__shfl_xor(s1,off,64);
      const float M=fmaxf(m1,mo); s1 = s1*__expf(m1-M) + so*__expf(mo-M); m1=M; }
  }
  if (c == 0){
    float2* pp = pa.pp + (size_t)pIdx*Bc*JS;
    pp[(size_t)r0*JS + jb]     = make_float2(m0, s0);
    pp[(size_t)(r0+1)*JS + jb] = make_float2(m1, s1);
  }
}

// merge: 8 x 512 blocks; per-row result -> mres[pIdx*Bc + b] (no atomics)
struct MergeArgs {
  const float* G[8]; const float* H[8];
  const float2* pp; float* mres;    // [8][Bc]
};

__global__ __launch_bounds__(256) void k_merge_all(MergeArgs ma){
  const int pIdx = blockIdx.x >> 9;
  const int sub = blockIdx.x & 511;
  const int w = threadIdx.x >> 6, lane = threadIdx.x & 63;
  const int b = sub*4 + w;
  const float* G = ma.G[pIdx];
  const float* H = ma.H[pIdx];
  const size_t o = ((size_t)b << 6) + lane;
  const float d = wsum(G[o]*H[o]) * INV_Tc;
  const float2* pp = ma.pp + (size_t)pIdx*Bc*JS + (size_t)b*JS;
  const float2 p0 = pp[0], p1 = pp[1], p2 = pp[2], p3 = pp[3];
  float res;
  if ((pIdx & 1) == 0){
    const float M = fmaxf(fmaxf(p0.x,p1.x), fmaxf(p2.x,p3.x));
    const float S = p0.y*__expf(p0.x-M) + p1.y*__expf(p1.x-M)
                  + p2.y*__expf(p2.x-M) + p3.y*__expf(p3.x-M);
    res = M + logf(S) - d;
  } else {
    const float S = p0.y*__expf(p0.x) + p1.y*__expf(p1.x)
                  + p2.y*__expf(p2.x) + p3.y*__expf(p3.x);
    res = -logf(__expf(d)/(S + 1e-8f) + 1e-8f);
  }
  if (lane == 0) ma.mres[(size_t)pIdx*Bc + b] = res;
}

// final: single block sums rbuf (loss_r) + mres (loss_g even pIdx, loss_h odd)
__global__ __launch_bounds__(256) void k_final(const float* __restrict__ rbuf,
                                               const float* __restrict__ mres,
                                               float* __restrict__ out){
  __shared__ float shm[3][4];
  const int t = threadIdx.x;
  float sr = 0.f, shh = 0.f, sg = 0.f;
  for (int i=t; i<Bc; i+=256) sr += rbuf[i];
  #pragma unroll
  for (int p=0;p<8;p++){
    float acc = 0.f;
    for (int i=t; i<Bc; i+=256) acc += mres[(size_t)p*Bc + i];
    if (p & 1) shh += acc; else sg += acc;
  }
  sr = wsum(sr); shh = wsum(shh); sg = wsum(sg);
  const int w = t >> 6;
  if ((t & 63) == 0){ shm[0][w] = sr; shm[1][w] = shh; shm[2][w] = sg; }
  __syncthreads();
  if (t == 0){
    float R=0.f, Hh=0.f, Gg=0.f;
    #pragma unroll
    for (int q=0;q<4;q++){ R += shm[0][q]; Hh += shm[1][q]; Gg += shm[2][q]; }
    const float lr = R / (float)Bc;
    out[0] = lr + LHYPERc*Hh + Gg;
    out[1] = lr; out[2] = Hh; out[3] = Gg;
  }
}

// ---------------- host launch ----------------
extern "C" void kernel_launch(void* const* d_in, const int* in_sizes, int n_in,
                              void* d_out, int out_size, void* d_ws, size_t ws_size,
                              hipStream_t stream){
  const float* E_u0 = (const float*)d_in[0];
  const float* E_i0 = (const float*)d_in[1];
  // d_in[2], d_in[3] (S_u_0, S_i_0): col 0 == 0 forever, payload == E_*_0 -> unused.
  const float* Ws   = (const float*)d_in[4];
  const float* adj  = (const float*)d_in[5];
  const float* keep = (const float*)d_in[6];
  const int* rows = (const int*)d_in[7];
  const int* cols = (const int*)d_in[8];
  const int* uids = (const int*)d_in[9];
  const int* iids = (const int*)d_in[10];
  const int* pos  = (const int*)d_in[11];
  const int* neg  = (const int*)d_in[12];
  float* out = (float*)d_out;

  char* wsb = (char*)d_ws;
  size_t off = 0;
  auto alloc = [&](size_t bytes)->void*{
    void* p = (void*)(wsb + off);
    off += (bytes + 255) & ~(size_t)255;
    return p;
  };

  int* cnt_u = (int*)alloc((size_t)N_Uc*4);
  int* ptr_u = (int*)alloc((size_t)(N_Uc+1)*4);
  int* cur_u = (int*)alloc((size_t)N_Uc*4);
  int* cnt_i = (int*)alloc((size_t)N_Ic*4);
  int* ptr_i = (int*)alloc((size_t)(N_Ic+1)*4);
  int* cur_i = (int*)alloc((size_t)N_Ic*4);
  int2* ent_u = (int2*)alloc((size_t)Ec*8);
  int2* ent_i = (int2*)alloc((size_t)Ec*8);
  int* tsum_u = (int*)alloc(256*4);
  int* tsum_i = (int*)alloc(256*4);

  float* Ecu0 = (float*)alloc((size_t)NU64*4);
  float* Ecu1 = (float*)alloc((size_t)NU64*4);
  float* Ecu2 = (float*)alloc((size_t)NU64*4);
  float* Eu_t = (float*)alloc((size_t)NU64*4);
  float* Eci0 = (float*)alloc((size_t)NI64*4);
  float* Eci1 = (float*)alloc((size_t)NI64*4);
  float* Eci2 = (float*)alloc((size_t)NI64*4);
  float* Ei_t = (float*)alloc((size_t)NI64*4);

  // saves: [layer][channel] per side (channels: 0=z, 1=zs, 2=zuu/zii)
  float* sv_u[2][3], *sv_i[2][3];
  for (int l=0;l<2;l++) for (int ch=0;ch<3;ch++){
    sv_u[l][ch] = (float*)alloc((size_t)B64*4);
    sv_i[l][ch] = (float*)alloc((size_t)B64*4);
  }
  float* nrm_g[4], *nrm_u[4], *hmat[4];
  for (int p=0;p<4;p++){
    nrm_g[p] = (float*)alloc((size_t)B64*4);
    nrm_u[p] = (float*)alloc((size_t)B64*4);
    hmat[p]  = (float*)alloc((size_t)B64*4);
  }
  float2* pp = (float2*)alloc((size_t)8*Bc*JS*8);
  float* rbuf = (float*)alloc((size_t)Bc*4);
  float* mres = (float*)alloc((size_t)8*Bc*4);
  // total ws use ~= 203 MB

  // ---- CSR/CSC build (6 launches) ----
  k_zero<<<NBF_U,256,0,stream>>>(cnt_u, cnt_i);
  k_hist<<<cdiv(Ec,256),256,0,stream>>>(rows, cols, cnt_u, cnt_i);
  k_scan_local<<<NTILE_U+NTILE_I,256,0,stream>>>(cnt_u, cnt_i, cur_u, cur_i, tsum_u, tsum_i);
  k_scan_tiles<<<2,256,0,stream>>>(tsum_u, tsum_i);
  k_scan_final<<<NBF_U+NBF_I,256,0,stream>>>(tsum_u, tsum_i, ptr_u, ptr_i, cur_u, cur_i);
  k_scatter<<<cdiv(Ec,256),256,0,stream>>>(rows, cols, adj, keep, cur_u, cur_i, ent_u, ent_i);

  // ---- layer 0 (1 launch) ----
  SpmmArgs sa{ptr_u, ent_u, ptr_i, ent_i, E_u0, E_i0,
              Ecu0, Ecu1, Ecu2, Eu_t, Eci0, Eci1, Eci2, Ei_t};
  k_spmm3_all<<<NB_SPU+NB_SPI,256,0,stream>>>(sa);

  // ---- layer 1 + sampled + layer-0 saves (1 launch) ----
  L1Args la{ptr_u, ent_u, ptr_i, ent_i, E_u0, E_i0,
            Ecu0, Ecu1, Ecu2, Eci0, Eci1, Eci2, Eu_t, Ei_t, uids, iids,
            sv_u[1][0], sv_u[1][1], sv_u[1][2], sv_i[1][0], sv_i[1][1], sv_i[1][2],
            sv_u[0][0], sv_u[0][1], sv_u[0][2], sv_i[0][0], sv_i[0][1], sv_i[0][2]};
  k_layer1_all<<<NB_SPU+NB_SPI+4*NB_B,256,0,stream>>>(la);

  // ---- loss prep (1 launch): p = l*2+side ----
  PrepArgs pra{};
  for (int l=0;l<2;l++) for (int side=0; side<2; side++){
    const int p = l*2+side;
    float** svs = side ? sv_i[l] : sv_u[l];
    pra.in[p]   = svs[0]; pra.out[p]   = nrm_g[p];
    pra.in[4+p] = svs[2]; pra.out[4+p] = nrm_u[p];
    pra.in[8+p] = svs[1]; pra.out[8+p] = hmat[p];
    pra.W[8+p]  = Ws + (size_t)l*65*65;
  }
  k_prep<<<12*NB_B,256,0,stream>>>(pra);

  // ---- pair scores + lossr (1 launch) ----
  PairArgs paa{};
  for (int p=0;p<4;p++){
    paa.G[2*p]   = nrm_g[p]; paa.H[2*p]   = nrm_u[p];   // loss_g
    paa.G[2*p+1] = nrm_g[p]; paa.H[2*p+1] = hmat[p];    // loss_h
  }
  paa.pp = pp; paa.uids = uids; paa.pos = pos; paa.neg = neg;
  paa.Eut = Eu_t; paa.Eit = Ei_t; paa.rbuf = rbuf;
  k_pair_all<<<4096+NB_B,256,0,stream>>>(paa);

  // ---- merge (1 launch) + final ----
  MergeArgs mga{};
  for (int p=0;p<8;p++){ mga.G[p] = paa.G[p]; mga.H[p] = paa.H[p]; }
  mga.pp = pp; mga.mres = mres;
  k_merge_all<<<8*NB_B,256,0,stream>>>(mga);

  k_final<<<1,256,0,stream>>>(rbuf, mres, out);
}